// Round 9
// baseline (191.518 us; speedup 1.0000x reference)
//
#include <hip/hip_runtime.h>

#define LOG2PI_F 1.8378770664093453f

// ---- workspace layout (float offsets) ----
#define W_ENC_PRE 0        // 512x64
#define W_INF_PRE 32768    // 512x64
#define W_FIN     65792    // 4: [s1acc][s2acc][ticket(uint)][pad] (zeroed by k_latAB)
#define W_MIMM    65796    // 256 float2 (mi per-block min/max)
#define W_DSMM    66308    // 512 float2 (dis per-block min/max)
#define W_ENT     67332    // 256
#define W_KL      67588    // 256
#define W_LATENT  67844    // 512x256 (16B aligned)
#define W_RPC     198916   // 512x256x4 interleaved (rr,pp,cc,0); 16B aligned
#define W_A       723204   // 512x64 [j][c]
#define W_B       755972   // 512x64
#define W_AT      788740   // 64x512 [c][j]
#define W_BT      821508   // 64x512
#define W_ALPHA   854276   // 512x64 [s][c]
#define W_BETA    887044   // 512x64
#define W_MI      919812   // 512x512 [p][j]
#define W_DIS     1181956  // 512x512 [p][j]
#define W_PACC    1446144  // 256 blocks x 256 partials

// ---------------------------------------------------------------------------
// K1: pre-BN activations (biases cancel in BN); per-block BN partials, no
// atomics, no init. [unchanged — proven]
__global__ __launch_bounds__(256) void k_pre(
    const float* __restrict__ obs, const float* __restrict__ hid,
    const float* __restrict__ eW1, const float* __restrict__ iW1,
    float* __restrict__ enc_pre, float* __restrict__ inf_pre,
    float* __restrict__ pacc) {
  __shared__ float x[2][720];
  __shared__ float pi[4][2][64];
  __shared__ float pe[4][2][64];
  __shared__ float sb[256];
  const int t = threadIdx.x;
  const int vb = blockIdx.x;
  const int i0 = vb * 2;
#pragma unroll
  for (int r = 0; r < 2; ++r)
    for (int k = t; k < 720; k += 256)
      x[r][k] = (k < 64) ? hid[(i0 + r) * 64 + k] : obs[(i0 + r) * 656 + (k - 64)];
  __syncthreads();
  const int c = t & 63, q = t >> 6;
  {
    float a0 = 0.f, a1 = 0.f;
    const int k0 = q * 180;
    for (int k = k0; k < k0 + 180; ++k) {
      const float w = iW1[k * 64 + c];
      a0 = fmaf(x[0][k], w, a0);
      a1 = fmaf(x[1][k], w, a1);
    }
    pi[q][0][c] = a0;
    pi[q][1][c] = a1;
  }
  {
    float a0 = 0.f, a1 = 0.f;
    const int k0 = q * 32;
    for (int k = k0; k < k0 + 32; ++k) {
      const float w = eW1[k * 64 + c];
      a0 = fmaf(x[0][592 + k], w, a0);
      a1 = fmaf(x[1][592 + k], w, a1);
    }
    pe[q][0][c] = a0;
    pe[q][1][c] = a1;
  }
  __syncthreads();
  float s;
  if (t < 128) {
    const int r = t >> 6, c2 = t & 63;
    s = pi[0][r][c2] + pi[1][r][c2] + pi[2][r][c2] + pi[3][r][c2];
    inf_pre[(i0 + r) * 64 + c2] = s;
  } else {
    const int r = (t >> 6) & 1, c2 = t & 63;
    s = pe[0][r][c2] + pe[1][r][c2] + pe[2][r][c2] + pe[3][r][c2];
    enc_pre[(i0 + r) * 64 + c2] = s;
  }
  sb[t] = s;
  __syncthreads();
  if (t < 64) {
    const float e0 = sb[128 + t], e1 = sb[192 + t];
    pacc[vb * 256 + t] = e0 + e1;
    pacc[vb * 256 + 64 + t] = e0 * e0 + e1 * e1;
  } else if (t < 128) {
    const int c2 = t - 64;
    const float v0 = sb[c2], v1 = sb[64 + c2];
    pacc[vb * 256 + 128 + c2] = v0 + v1;
    pacc[vb * 256 + 192 + c2] = v0 * v0 + v1 * v1;
  }
}

// ---------------------------------------------------------------------------
// K2: FUSED lat+AB. Row mapping identical (block b owns rows 2b,2b+1), so
// the AB body consumes the latent values just computed — no global reload,
// one fewer node. FIN zero moved here (2 nodes ahead of k_sumfin).
__global__ __launch_bounds__(256) void k_latAB(
    const float* __restrict__ enc_pre, const float* __restrict__ inf_pre,
    const float* __restrict__ pacc, const float* __restrict__ eg,
    const float* __restrict__ ebt, const float* __restrict__ ig,
    const float* __restrict__ ibt, const float* __restrict__ eW2,
    const float* __restrict__ eb2, const float* __restrict__ iW2,
    const float* __restrict__ ib2, const float* __restrict__ eps,
    const float* __restrict__ dW1, float* __restrict__ latent,
    float* __restrict__ rpc, float* __restrict__ ent_part,
    float* __restrict__ kl_part, float* __restrict__ A, float* __restrict__ B,
    float* __restrict__ At, float* __restrict__ Bt, float* __restrict__ fin) {
  __shared__ float sval[256];
  __shared__ float sc[2][64], sh[2][64];
  __shared__ float h[2][2][64];
  __shared__ float red[256];
  __shared__ float ls[2][256];
  __shared__ float pA[4][2][64], pB[4][2][64];
  const int t = threadIdx.x;
  const int i0 = blockIdx.x * 2;
  if (blockIdx.x == 0 && t == 0) {
    fin[0] = 0.f;
    fin[1] = 0.f;
    ((unsigned*)fin)[2] = 0u;
  }
  {
    float v = 0.f;
    for (int b = 0; b < 256; ++b) v += pacc[b * 256 + t];
    sval[t] = v;
  }
  __syncthreads();
  if (t < 128) {
    const int w = t >> 6, c = t & 63;
    const float sum = sval[w * 128 + c], sq = sval[w * 128 + 64 + c];
    const float mean = sum * (1.f / 512.f);
    float var = sq * (1.f / 512.f) - mean * mean;
    var = fmaxf(var, 0.f);
    const float g = w ? ig[c] : eg[c];
    const float bt = w ? ibt[c] : ebt[c];
    const float scale = g * rsqrtf(var + 1e-5f);
    sc[w][c] = scale;
    sh[w][c] = bt - mean * scale;
  }
  __syncthreads();
  {
    const int w = t >> 7, r = (t >> 6) & 1, c = t & 63;
    const float* pre = w ? inf_pre : enc_pre;
    const float v = fmaf(pre[(i0 + r) * 64 + c], sc[w][c], sh[w][c]);
    h[w][r][c] = (v >= 0.f) ? v : 0.01f * v;
  }
  __syncthreads();
  float me[2] = {0.f, 0.f}, ve[2] = {0.f, 0.f};
  float mq[2] = {0.f, 0.f}, vq[2] = {0.f, 0.f};
  for (int c = 0; c < 64; ++c) {
    const float we1 = eW2[c * 512 + t], we2 = eW2[c * 512 + 256 + t];
    const float wi1 = iW2[c * 512 + t], wi2 = iW2[c * 512 + 256 + t];
#pragma unroll
    for (int r = 0; r < 2; ++r) {
      me[r] = fmaf(h[0][r][c], we1, me[r]);
      ve[r] = fmaf(h[0][r][c], we2, ve[r]);
      mq[r] = fmaf(h[1][r][c], wi1, mq[r]);
      vq[r] = fmaf(h[1][r][c], wi2, vq[r]);
    }
  }
  const float ebm = eb2[t], ebv = eb2[256 + t];
  const float ibm = ib2[t], ibv = ib2[256 + t];
  float ent_l = 0.f, kl_l = 0.f;
  float latv[2];
#pragma unroll
  for (int r = 0; r < 2; ++r) {
    const int i = i0 + r;
    const float m = me[r] + ebm;
    const float var = fmaxf(expf(ve[r] + ebv), 0.002f);
    const float lse = 0.5f * logf(var);
    const float sig = sqrtf(var);
    const float mqq = mq[r] + ibm;
    const float varq = fmaxf(expf(vq[r] + ibv), 0.002f);
    const float lsq = 0.5f * logf(varq);
    latv[r] = fmaf(sig, eps[i * 256 + t], m);
    latent[i * 256 + t] = latv[r];
    const float r_ = sqrtf(0.5f / var);
    float4 o;
    o.x = r_;
    o.y = m * r_;
    o.z = 13.9f - 0.5f * LOG2PI_F - lse;
    o.w = 0.f;
    *(float4*)&rpc[(i * 256 + t) * 4] = o;
    ent_l += 0.5f + 0.5f * LOG2PI_F + lse;
    const float dmu = m - mqq;
    kl_l += lsq - lse + (var + dmu * dmu) * (0.5f / varq) - 0.5f;
  }
  red[t] = ent_l;
  ls[0][t] = latv[0];
  ls[1][t] = latv[1];
  __syncthreads();
  for (int o = 128; o; o >>= 1) {
    if (t < o) red[t] += red[t + o];
    __syncthreads();
  }
  if (t == 0) ent_part[blockIdx.x] = red[0];
  __syncthreads();
  red[t] = kl_l;
  __syncthreads();
  for (int o = 128; o; o >>= 1) {
    if (t < o) red[t] += red[t + o];
    __syncthreads();
  }
  if (t == 0) kl_part[blockIdx.x] = red[0];
  // ---- AB body (verbatim R8 k_AB, ls already in LDS) ----
  const int c = t & 63, q = t >> 6;
  const int j0 = i0;
  float aA0 = 0.f, aA1 = 0.f, aB0 = 0.f, aB1 = 0.f;
  const int k0 = q * 64;
  for (int k = k0; k < k0 + 64; ++k) {
    const float wA = dW1[k * 64 + c];
    const float wB = dW1[(256 + k) * 64 + c];
    aA0 = fmaf(ls[0][k], wA, aA0);
    aA1 = fmaf(ls[1][k], wA, aA1);
    aB0 = fmaf(ls[0][k], wB, aB0);
    aB1 = fmaf(ls[1][k], wB, aB1);
  }
  pA[q][0][c] = aA0;
  pA[q][1][c] = aA1;
  pB[q][0][c] = aB0;
  pB[q][1][c] = aB1;
  __syncthreads();
  if (t < 128) {
    const int r = t >> 6, c2 = t & 63;
    const float s = pA[0][r][c2] + pA[1][r][c2] + pA[2][r][c2] + pA[3][r][c2];
    A[(j0 + r) * 64 + c2] = s;
    At[c2 * 512 + j0 + r] = s;
  } else {
    const int r = (t >> 6) & 1, c2 = t & 63;
    const float s = pB[0][r][c2] + pB[1][r][c2] + pB[2][r][c2] + pB[3][r][c2];
    B[(j0 + r) * 64 + c2] = s;
    Bt[c2 * 512 + j0 + r] = s;
  }
}

// ---------------------------------------------------------------------------
// K3: per-(s,c) BN affine via circular correlation. [unchanged — proven]
__global__ __launch_bounds__(256) void k_cross(
    const float* __restrict__ At, const float* __restrict__ Bt,
    const float* __restrict__ dg, const float* __restrict__ dbt,
    float* __restrict__ alpha, float* __restrict__ beta) {
  __shared__ float a[512], bb[512];
  __shared__ float red[256];
  __shared__ float pc[4][64];
  const int t = threadIdx.x;
  const int c = blockIdx.x >> 3;
  const int s0 = (blockIdx.x & 7) * 64;
  const float a0 = At[c * 512 + t], a1 = At[c * 512 + 256 + t];
  const float b0 = Bt[c * 512 + t], b1 = Bt[c * 512 + 256 + t];
  a[t] = a0;
  a[t + 256] = a1;
  bb[t] = b0;
  bb[t + 256] = b1;
  red[t] = a0 + a1 + b0 + b1;
  __syncthreads();
  for (int o = 128; o; o >>= 1) {
    if (t < o) red[t] += red[t + o];
    __syncthreads();
  }
  const float S = red[0];
  __syncthreads();
  red[t] = a0 * a0 + a1 * a1 + b0 * b0 + b1 * b1;
  __syncthreads();
  for (int o = 128; o; o >>= 1) {
    if (t < o) red[t] += red[t + o];
    __syncthreads();
  }
  const float Q = red[0];
  const int sl = t & 63, part = t >> 6;
  const int s = s0 + sl;
  float cr = 0.f;
  for (int j = part * 128; j < part * 128 + 128; ++j)
    cr = fmaf(a[j], bb[(j - s - 1) & 511], cr);
  pc[part][sl] = cr;
  __syncthreads();
  if (t < 64) {
    const int ss = s0 + t;
    const float cross = pc[0][t] + pc[1][t] + pc[2][t] + pc[3][t];
    const float mean = S * (1.f / 512.f);
    const float var = (Q + 2.f * cross) * (1.f / 512.f) - mean * mean;
    const float gc = dg[c], bc = dbt[c];
    const float al = rsqrtf(var + 1e-5f) * gc;
    alpha[ss * 64 + c] = al;
    beta[ss * 64 + c] = bc - mean * al;
  }
}

// ---------------------------------------------------------------------------
// K4: fused mi+dis, bodies verbatim; mi = even blocks < 512 so each CU's two
// co-resident blocks mix the LDS-heavy mi body with the VALU-heavy dis body.
__global__ __launch_bounds__(256) void k_midis(
    const float* __restrict__ latent, const float* __restrict__ rpc,
    const float* __restrict__ A, const float* __restrict__ B,
    const float* __restrict__ alpha, const float* __restrict__ beta,
    const float* __restrict__ dW2, const float* __restrict__ db2,
    float* __restrict__ mi, float* __restrict__ dis,
    float2* __restrict__ miMM, float2* __restrict__ dsMM) {
  __shared__ __align__(16) float sm[15276];  // 61,104 B
  const int t = threadIdx.x;
  const bool is_mi = (blockIdx.x < 512) && ((blockIdx.x & 1) == 0);
  if (is_mi) {
    // ---- mi body ----
    float* lats = sm;
    float* rpcs = sm + 4160;
    float* mt = sm + 8256;
    float* fmn = sm + 9344;
    float* fmx = sm + 9600;
    const int vb = blockIdx.x >> 1;
    const int jt = vb & 31, pt = vb >> 5;
    const int j0 = jt * 16, p0 = pt * 64;
    const int pl = t & 31, jg = t >> 5;
    float regL[16], regR[16];
#pragma unroll
    for (int i = 0; i < 16; ++i) {
      const int idx = t + i * 256;
      regL[i] = latent[(p0 + (idx >> 6)) * 256 + (idx & 63)];
      regR[i] = rpc[(j0 + (idx >> 8)) * 1024 + (idx & 255)];
    }
    float a00 = 0.f, a01 = 0.f, a10 = 0.f, a11 = 0.f;
    for (int kc = 0; kc < 4; ++kc) {
      __syncthreads();
#pragma unroll
      for (int i = 0; i < 16; ++i) {
        const int idx = t + i * 256;
        lats[(idx >> 6) * 65 + (idx & 63)] = regL[i];
        rpcs[idx] = regR[i];
      }
      __syncthreads();
      if (kc < 3) {
#pragma unroll
        for (int i = 0; i < 16; ++i) {
          const int idx = t + i * 256;
          regL[i] = latent[(p0 + (idx >> 6)) * 256 + (kc + 1) * 64 + (idx & 63)];
          regR[i] = rpc[(j0 + (idx >> 8)) * 1024 + (kc + 1) * 256 + (idx & 255)];
        }
      }
      const float4* rp0 = (const float4*)&rpcs[(jg * 2) * 256];
      const float4* rp1 = (const float4*)&rpcs[(jg * 2 + 1) * 256];
#pragma unroll 8
      for (int k = 0; k < 64; ++k) {
        const float l0 = lats[pl * 65 + k], l1 = lats[(pl + 32) * 65 + k];
        const float4 r0 = rp0[k];
        const float4 r1 = rp1[k];
        float v;
        v = fmaf(l0, r0.x, -r0.y);
        a00 += fmaxf(fmaf(-v, v, r0.z), -13.9f);
        v = fmaf(l1, r0.x, -r0.y);
        a01 += fmaxf(fmaf(-v, v, r0.z), -13.9f);
        v = fmaf(l0, r1.x, -r1.y);
        a10 += fmaxf(fmaf(-v, v, r1.z), -13.9f);
        v = fmaf(l1, r1.x, -r1.y);
        a11 += fmaxf(fmaf(-v, v, r1.z), -13.9f);
      }
    }
    a00 *= (1.f / 256.f);
    a01 *= (1.f / 256.f);
    a10 *= (1.f / 256.f);
    a11 *= (1.f / 256.f);
    __syncthreads();
    mt[pl * 17 + jg * 2] = a00;
    mt[(pl + 32) * 17 + jg * 2] = a01;
    mt[pl * 17 + jg * 2 + 1] = a10;
    mt[(pl + 32) * 17 + jg * 2 + 1] = a11;
    fmn[t] = fminf(fminf(a00, a01), fminf(a10, a11));
    fmx[t] = fmaxf(fmaxf(a00, a01), fmaxf(a10, a11));
    __syncthreads();
    for (int o = 128; o; o >>= 1) {
      if (t < o) {
        fmn[t] = fminf(fmn[t], fmn[t + o]);
        fmx[t] = fmaxf(fmx[t], fmx[t + o]);
      }
      __syncthreads();
    }
    if (t == 0) miMM[vb] = make_float2(fmn[0], fmx[0]);
    for (int i = t; i < 1024; i += 256) {
      const int pr = i >> 4, jc = i & 15;
      mi[(p0 + pr) * 512 + (j0 + jc)] = mt[pr * 17 + jc];
    }
  } else {
    // ---- dis body ----
    float* As = sm;
    float* Bs = sm + 528;
    float* als = sm + 4752;
    float* bes = sm + 9438;
    float* w2s = sm + 14124;
    float* dt = sm + 14188;
    float* fmn = sm + 14764;
    float* fmx = sm + 15020;
    const int vb = (blockIdx.x < 512) ? (int)(blockIdx.x >> 1)
                                      : (int)(blockIdx.x - 256);
    const int jt = vb & 63, pt = vb >> 6;
    const int j0 = jt * 8, p0 = pt * 64;
    for (int idx = t; idx < 8 * 64; idx += 256)
      As[(idx >> 6) * 66 + (idx & 63)] = A[(j0 + (idx >> 6)) * 64 + (idx & 63)];
    for (int idx = t; idx < 64 * 64; idx += 256)
      Bs[(idx >> 6) * 66 + (idx & 63)] = B[(p0 + (idx >> 6)) * 64 + (idx & 63)];
    for (int idx = t; idx < 71 * 64; idx += 256) {
      const int r = idx >> 6, c = idx & 63;
      const int s = (j0 - p0 - 64 + r) & 511;
      als[r * 66 + c] = alpha[s * 64 + c];
      bes[r * 66 + c] = beta[s * 64 + c];
    }
    if (t < 64) w2s[t] = dW2[t];
    const float db2v = db2[0];
    __syncthreads();
    const int pl = t & 31, jg = t >> 5;
    const int rb0 = jg - pl + 63;
    const int rb1 = jg - pl + 31;
    float acc0 = 0.f, acc1 = 0.f;
    for (int c = 0; c < 64; c += 2) {
      const float2 av = *(const float2*)&As[jg * 66 + c];
      const float2 bv0 = *(const float2*)&Bs[pl * 66 + c];
      const float2 bv1 = *(const float2*)&Bs[(pl + 32) * 66 + c];
      const float2 al0 = *(const float2*)&als[rb0 * 66 + c];
      const float2 al1 = *(const float2*)&als[rb1 * 66 + c];
      const float2 be0 = *(const float2*)&bes[rb0 * 66 + c];
      const float2 be1 = *(const float2*)&bes[rb1 * 66 + c];
      const float2 w = *(const float2*)&w2s[c];
      float v;
      v = fmaf(av.x + bv0.x, al0.x, be0.x);
      v = (v >= 0.f) ? v : 0.01f * v;
      acc0 = fmaf(v, w.x, acc0);
      v = fmaf(av.y + bv0.y, al0.y, be0.y);
      v = (v >= 0.f) ? v : 0.01f * v;
      acc0 = fmaf(v, w.y, acc0);
      v = fmaf(av.x + bv1.x, al1.x, be1.x);
      v = (v >= 0.f) ? v : 0.01f * v;
      acc1 = fmaf(v, w.x, acc1);
      v = fmaf(av.y + bv1.y, al1.y, be1.y);
      v = (v >= 0.f) ? v : 0.01f * v;
      acc1 = fmaf(v, w.y, acc1);
    }
    acc0 = fabsf(acc0 + db2v);
    acc1 = fabsf(acc1 + db2v);
    dt[pl * 9 + jg] = acc0;
    dt[(pl + 32) * 9 + jg] = acc1;
    fmn[t] = fminf(acc0, acc1);
    fmx[t] = fmaxf(acc0, acc1);
    __syncthreads();
    for (int o = 128; o; o >>= 1) {
      if (t < o) {
        fmn[t] = fminf(fmn[t], fmn[t + o]);
        fmx[t] = fmaxf(fmx[t], fmx[t + o]);
      }
      __syncthreads();
    }
    if (t == 0) dsMM[vb] = make_float2(fmn[0], fmx[0]);
    for (int idx = t; idx < 512; idx += 256) {
      const int pr = idx >> 3, jc = idx & 7;
      dis[(p0 + pr) * 512 + (j0 + jc)] = dt[pr * 9 + jc];
    }
  }
}

// ---------------------------------------------------------------------------
// K5: minmax + normalize + sums + ticketed final; main pass vectorized to
// exactly one float4 of mi and dis per thread.
__global__ __launch_bounds__(256) void k_sumfin(
    const float* __restrict__ mi, const float* __restrict__ dis,
    const float2* __restrict__ miMM, const float2* __restrict__ dsMM,
    float* __restrict__ fin, const float* __restrict__ ent_part,
    const float* __restrict__ kl_part, float* __restrict__ out) {
  __shared__ float red1[256], red2[256], red3[256], red4[256];
  __shared__ int lastflag;
  const int t = threadIdx.x;
  {
    const float2 v = miMM[t];
    const float2 w0 = dsMM[t], w1 = dsMM[t + 256];
    red1[t] = v.x;
    red2[t] = v.y;
    red3[t] = fminf(w0.x, w1.x);
    red4[t] = fmaxf(w0.y, w1.y);
  }
  __syncthreads();
  for (int o = 128; o; o >>= 1) {
    if (t < o) {
      red1[t] = fminf(red1[t], red1[t + o]);
      red2[t] = fmaxf(red2[t], red2[t + o]);
      red3[t] = fminf(red3[t], red3[t + o]);
      red4[t] = fmaxf(red4[t], red4[t + o]);
    }
    __syncthreads();
  }
  const float mi_mn = red1[0], mi_mx = red2[0];
  const float d_mn = red3[0], d_mx = red4[0];
  __syncthreads();
  const float inv_mi = 1.f / (mi_mx - mi_mn + 1e-12f);
  const float inv_d = 1.f / (d_mx - d_mn + 1e-12f);
  float s1 = 0.f, s2 = 0.f;
  {
    const int idx = blockIdx.x * 256 + t;  // 65536 threads x 1 float4 each
    const float4 m4 = ((const float4*)mi)[idx];
    const float4 d4 = ((const float4*)dis)[idx];
    float mn_, dn_;
    mn_ = (m4.x - mi_mn) * inv_mi;
    dn_ = (d4.x - d_mn) * inv_d;
    s1 += fminf(mn_ + dn_, 1.0f);
    s2 += dn_;
    mn_ = (m4.y - mi_mn) * inv_mi;
    dn_ = (d4.y - d_mn) * inv_d;
    s1 += fminf(mn_ + dn_, 1.0f);
    s2 += dn_;
    mn_ = (m4.z - mi_mn) * inv_mi;
    dn_ = (d4.z - d_mn) * inv_d;
    s1 += fminf(mn_ + dn_, 1.0f);
    s2 += dn_;
    mn_ = (m4.w - mi_mn) * inv_mi;
    dn_ = (d4.w - d_mn) * inv_d;
    s1 += fminf(mn_ + dn_, 1.0f);
    s2 += dn_;
  }
  red1[t] = s1;
  red2[t] = s2;
  __syncthreads();
  for (int o = 128; o; o >>= 1) {
    if (t < o) {
      red1[t] += red1[t + o];
      red2[t] += red2[t + o];
    }
    __syncthreads();
  }
  if (t == 0) {
    atomicAdd(&fin[0], red1[0]);
    atomicAdd(&fin[1], red2[0]);
    __threadfence();
    const unsigned old = atomicAdd((unsigned*)&fin[2], 1u);
    lastflag = (old == 255u) ? 1 : 0;
  }
  __syncthreads();
  if (!lastflag) return;
  red1[t] = ent_part[t];
  red2[t] = kl_part[t];
  __syncthreads();
  for (int o = 128; o; o >>= 1) {
    if (t < o) {
      red1[t] += red1[t + o];
      red2[t] += red2[t + o];
    }
    __syncthreads();
  }
  if (t == 0) {
    const float S1 = atomicAdd(&fin[0], 0.f);
    const float S2 = atomicAdd(&fin[1], 0.f);
    const double entropy = (double)red1[0] / 512.0;
    const double kl = (double)red2[0] / 512.0;
    double l0 = entropy * 1e-4 + kl * 1e-4;
    if (l0 > 2000.0) l0 = 2000.0;
    const double ce = log1p(exp(l0));
    const double dis_loss = -(double)S1 / 512.0;
    const double dis_norm = (double)S2 / 512.0;
    const double c_dis = (dis_norm + dis_loss) / 512.0;
    out[0] = (float)(ce + c_dis);
    out[1] = (float)c_dis;
    out[2] = (float)ce;
  }
}

// ---------------------------------------------------------------------------
extern "C" void kernel_launch(void* const* d_in, const int* in_sizes, int n_in,
                              void* d_out, int out_size, void* d_ws,
                              size_t ws_size, hipStream_t stream) {
  (void)in_sizes;
  (void)n_in;
  (void)out_size;
  (void)ws_size;
  const float* obs = (const float*)d_in[0];
  const float* hid = (const float*)d_in[1];
  const float* eps = (const float*)d_in[2];
  const float* eW1 = (const float*)d_in[3];
  const float* eg = (const float*)d_in[5];
  const float* ebt = (const float*)d_in[6];
  const float* eW2 = (const float*)d_in[7];
  const float* eb2 = (const float*)d_in[8];
  const float* iW1 = (const float*)d_in[9];
  const float* ig = (const float*)d_in[11];
  const float* ibt = (const float*)d_in[12];
  const float* iW2 = (const float*)d_in[13];
  const float* ib2 = (const float*)d_in[14];
  const float* dW1 = (const float*)d_in[15];
  const float* dg = (const float*)d_in[17];
  const float* dbt = (const float*)d_in[18];
  const float* dW2 = (const float*)d_in[19];
  const float* db2 = (const float*)d_in[20];
  float* ws = (float*)d_ws;
  float* out = (float*)d_out;

  k_pre<<<256, 256, 0, stream>>>(obs, hid, eW1, iW1, ws + W_ENC_PRE,
                                 ws + W_INF_PRE, ws + W_PACC);
  k_latAB<<<256, 256, 0, stream>>>(ws + W_ENC_PRE, ws + W_INF_PRE, ws + W_PACC,
                                   eg, ebt, ig, ibt, eW2, eb2, iW2, ib2, eps,
                                   dW1, ws + W_LATENT, ws + W_RPC, ws + W_ENT,
                                   ws + W_KL, ws + W_A, ws + W_B, ws + W_AT,
                                   ws + W_BT, ws + W_FIN);
  k_cross<<<512, 256, 0, stream>>>(ws + W_AT, ws + W_BT, dg, dbt, ws + W_ALPHA,
                                   ws + W_BETA);
  k_midis<<<768, 256, 0, stream>>>(ws + W_LATENT, ws + W_RPC, ws + W_A,
                                   ws + W_B, ws + W_ALPHA, ws + W_BETA, dW2,
                                   db2, ws + W_MI, ws + W_DIS,
                                   (float2*)(ws + W_MIMM),
                                   (float2*)(ws + W_DSMM));
  k_sumfin<<<256, 256, 0, stream>>>(ws + W_MI, ws + W_DIS,
                                    (const float2*)(ws + W_MIMM),
                                    (const float2*)(ws + W_DSMM), ws + W_FIN,
                                    ws + W_ENT, ws + W_KL, out);
}

// Round 10
// 178.305 us; speedup vs baseline: 1.0741x; 1.0741x over previous
//
#include <hip/hip_runtime.h>

#define LOG2PI_F 1.8378770664093453f

// ---- workspace layout (float offsets) ----
#define W_ENC_PRE 0        // 512x64
#define W_INF_PRE 32768    // 512x64
#define W_FIN     65792    // 4: [s1acc][s2acc][ticket(uint)][pad] (zeroed by k_latAB)
#define W_MIMM    65796    // 256 float2 (mi per-block min/max)
#define W_DSMM    66308    // 512 float2 (dis per-block min/max)
#define W_ENT     67332    // 256
#define W_KL      67588    // 256
#define W_LATENT  67844    // 512x256 (16B aligned)
#define W_RPC     198916   // 512x256x4 interleaved (rr,pp,cc,0); 16B aligned
#define W_A       723204   // 512x64 [j][c]
#define W_B       755972   // 512x64
#define W_AT      788740   // 64x512 [c][j]
#define W_BT      821508   // 64x512
#define W_ALPHA   854276   // 512x64 [s][c]
#define W_BETA    887044   // 512x64
#define W_MI      919812   // 512x512 [p][j]
#define W_DIS     1181956  // 512x512 [p][j]
#define W_PACC    1446144  // 256 blocks x 256 partials (16B aligned)

// ---------------------------------------------------------------------------
// K1: pre-BN activations (biases cancel in BN); per-block BN partials.
// Weight loops unrolled 8 so the compiler batches loads per waitcnt
// (R9 lesson: un-unrolled global-load loops at 1 wave/SIMD expose full
// latency per iteration).
__global__ __launch_bounds__(256) void k_pre(
    const float* __restrict__ obs, const float* __restrict__ hid,
    const float* __restrict__ eW1, const float* __restrict__ iW1,
    float* __restrict__ enc_pre, float* __restrict__ inf_pre,
    float* __restrict__ pacc) {
  __shared__ float x[2][720];
  __shared__ float pi[4][2][64];
  __shared__ float pe[4][2][64];
  __shared__ float sb[256];
  const int t = threadIdx.x;
  const int vb = blockIdx.x;
  const int i0 = vb * 2;
#pragma unroll
  for (int r = 0; r < 2; ++r)
    for (int k = t; k < 720; k += 256)
      x[r][k] = (k < 64) ? hid[(i0 + r) * 64 + k] : obs[(i0 + r) * 656 + (k - 64)];
  __syncthreads();
  const int c = t & 63, q = t >> 6;
  {
    float a0 = 0.f, a1 = 0.f;
    const int k0 = q * 180;
#pragma unroll 8
    for (int k = k0; k < k0 + 180; ++k) {
      const float w = iW1[k * 64 + c];
      a0 = fmaf(x[0][k], w, a0);
      a1 = fmaf(x[1][k], w, a1);
    }
    pi[q][0][c] = a0;
    pi[q][1][c] = a1;
  }
  {
    float a0 = 0.f, a1 = 0.f;
    const int k0 = q * 32;
#pragma unroll 8
    for (int k = k0; k < k0 + 32; ++k) {
      const float w = eW1[k * 64 + c];
      a0 = fmaf(x[0][592 + k], w, a0);
      a1 = fmaf(x[1][592 + k], w, a1);
    }
    pe[q][0][c] = a0;
    pe[q][1][c] = a1;
  }
  __syncthreads();
  float s;
  if (t < 128) {
    const int r = t >> 6, c2 = t & 63;
    s = pi[0][r][c2] + pi[1][r][c2] + pi[2][r][c2] + pi[3][r][c2];
    inf_pre[(i0 + r) * 64 + c2] = s;
  } else {
    const int r = (t >> 6) & 1, c2 = t & 63;
    s = pe[0][r][c2] + pe[1][r][c2] + pe[2][r][c2] + pe[3][r][c2];
    enc_pre[(i0 + r) * 64 + c2] = s;
  }
  sb[t] = s;
  __syncthreads();
  if (t < 64) {
    const float e0 = sb[128 + t], e1 = sb[192 + t];
    pacc[vb * 256 + t] = e0 + e1;
    pacc[vb * 256 + 64 + t] = e0 * e0 + e1 * e1;
  } else if (t < 128) {
    const int c2 = t - 64;
    const float v0 = sb[c2], v1 = sb[64 + c2];
    pacc[vb * 256 + 128 + c2] = v0 + v1;
    pacc[vb * 256 + 192 + c2] = v0 * v0 + v1 * v1;
  }
}

// ---------------------------------------------------------------------------
// K2: FUSED lat+AB. pacc reduction rebuilt as float4 quarter-split (64 wide
// loads, 2 accumulators) replacing the 256-iteration serial scalar loop that
// made R9's k_latAB the top dispatch (42 us, VALUBusy 6%).
__global__ __launch_bounds__(256) void k_latAB(
    const float* __restrict__ enc_pre, const float* __restrict__ inf_pre,
    const float* __restrict__ pacc, const float* __restrict__ eg,
    const float* __restrict__ ebt, const float* __restrict__ ig,
    const float* __restrict__ ibt, const float* __restrict__ eW2,
    const float* __restrict__ eb2, const float* __restrict__ iW2,
    const float* __restrict__ ib2, const float* __restrict__ eps,
    const float* __restrict__ dW1, float* __restrict__ latent,
    float* __restrict__ rpc, float* __restrict__ ent_part,
    float* __restrict__ kl_part, float* __restrict__ A, float* __restrict__ B,
    float* __restrict__ At, float* __restrict__ Bt, float* __restrict__ fin) {
  __shared__ float sval[256];
  __shared__ float pr4[4][64][4];
  __shared__ float sc[2][64], sh[2][64];
  __shared__ float h[2][2][64];
  __shared__ float red[256];
  __shared__ float ls[2][256];
  __shared__ float pA[4][2][64], pB[4][2][64];
  const int t = threadIdx.x;
  const int i0 = blockIdx.x * 2;
  if (blockIdx.x == 0 && t == 0) {
    fin[0] = 0.f;
    fin[1] = 0.f;
    ((unsigned*)fin)[2] = 0u;
  }
  {
    // pacc: [256 rows][64 float4]; quarter q sums rows q, q+4, ... (64 rows)
    const int fc = t & 63, q = t >> 6;
    const float4* p4 = (const float4*)pacc;
    float4 s0 = make_float4(0.f, 0.f, 0.f, 0.f);
    float4 s1 = make_float4(0.f, 0.f, 0.f, 0.f);
#pragma unroll 8
    for (int i = 0; i < 64; i += 2) {
      const float4 x0 = p4[(q + 4 * i) * 64 + fc];
      const float4 x1 = p4[(q + 4 * (i + 1)) * 64 + fc];
      s0.x += x0.x; s0.y += x0.y; s0.z += x0.z; s0.w += x0.w;
      s1.x += x1.x; s1.y += x1.y; s1.z += x1.z; s1.w += x1.w;
    }
    pr4[q][fc][0] = s0.x + s1.x;
    pr4[q][fc][1] = s0.y + s1.y;
    pr4[q][fc][2] = s0.z + s1.z;
    pr4[q][fc][3] = s0.w + s1.w;
  }
  __syncthreads();
  {
    const int fc = t >> 2, lane = t & 3;  // col = fc*4 + lane
    sval[t] = pr4[0][fc][lane] + pr4[1][fc][lane] + pr4[2][fc][lane] +
              pr4[3][fc][lane];
  }
  __syncthreads();
  if (t < 128) {
    const int w = t >> 6, c = t & 63;
    const float sum = sval[w * 128 + c], sq = sval[w * 128 + 64 + c];
    const float mean = sum * (1.f / 512.f);
    float var = sq * (1.f / 512.f) - mean * mean;
    var = fmaxf(var, 0.f);
    const float g = w ? ig[c] : eg[c];
    const float bt = w ? ibt[c] : ebt[c];
    const float scale = g * rsqrtf(var + 1e-5f);
    sc[w][c] = scale;
    sh[w][c] = bt - mean * scale;
  }
  __syncthreads();
  {
    const int w = t >> 7, r = (t >> 6) & 1, c = t & 63;
    const float* pre = w ? inf_pre : enc_pre;
    const float v = fmaf(pre[(i0 + r) * 64 + c], sc[w][c], sh[w][c]);
    h[w][r][c] = (v >= 0.f) ? v : 0.01f * v;
  }
  __syncthreads();
  float me[2] = {0.f, 0.f}, ve[2] = {0.f, 0.f};
  float mq[2] = {0.f, 0.f}, vq[2] = {0.f, 0.f};
#pragma unroll 8
  for (int c = 0; c < 64; ++c) {
    const float we1 = eW2[c * 512 + t], we2 = eW2[c * 512 + 256 + t];
    const float wi1 = iW2[c * 512 + t], wi2 = iW2[c * 512 + 256 + t];
#pragma unroll
    for (int r = 0; r < 2; ++r) {
      me[r] = fmaf(h[0][r][c], we1, me[r]);
      ve[r] = fmaf(h[0][r][c], we2, ve[r]);
      mq[r] = fmaf(h[1][r][c], wi1, mq[r]);
      vq[r] = fmaf(h[1][r][c], wi2, vq[r]);
    }
  }
  const float ebm = eb2[t], ebv = eb2[256 + t];
  const float ibm = ib2[t], ibv = ib2[256 + t];
  float ent_l = 0.f, kl_l = 0.f;
  float latv[2];
#pragma unroll
  for (int r = 0; r < 2; ++r) {
    const int i = i0 + r;
    const float m = me[r] + ebm;
    const float var = fmaxf(expf(ve[r] + ebv), 0.002f);
    const float lse = 0.5f * logf(var);
    const float sig = sqrtf(var);
    const float mqq = mq[r] + ibm;
    const float varq = fmaxf(expf(vq[r] + ibv), 0.002f);
    const float lsq = 0.5f * logf(varq);
    latv[r] = fmaf(sig, eps[i * 256 + t], m);
    latent[i * 256 + t] = latv[r];
    const float r_ = sqrtf(0.5f / var);
    float4 o;
    o.x = r_;
    o.y = m * r_;
    o.z = 13.9f - 0.5f * LOG2PI_F - lse;
    o.w = 0.f;
    *(float4*)&rpc[(i * 256 + t) * 4] = o;
    ent_l += 0.5f + 0.5f * LOG2PI_F + lse;
    const float dmu = m - mqq;
    kl_l += lsq - lse + (var + dmu * dmu) * (0.5f / varq) - 0.5f;
  }
  red[t] = ent_l;
  ls[0][t] = latv[0];
  ls[1][t] = latv[1];
  __syncthreads();
  for (int o = 128; o; o >>= 1) {
    if (t < o) red[t] += red[t + o];
    __syncthreads();
  }
  if (t == 0) ent_part[blockIdx.x] = red[0];
  __syncthreads();
  red[t] = kl_l;
  __syncthreads();
  for (int o = 128; o; o >>= 1) {
    if (t < o) red[t] += red[t + o];
    __syncthreads();
  }
  if (t == 0) kl_part[blockIdx.x] = red[0];
  // ---- AB body (ls already in LDS) ----
  const int c = t & 63, q = t >> 6;
  const int j0 = i0;
  float aA0 = 0.f, aA1 = 0.f, aB0 = 0.f, aB1 = 0.f;
  const int k0 = q * 64;
#pragma unroll 8
  for (int k = k0; k < k0 + 64; ++k) {
    const float wA = dW1[k * 64 + c];
    const float wB = dW1[(256 + k) * 64 + c];
    aA0 = fmaf(ls[0][k], wA, aA0);
    aA1 = fmaf(ls[1][k], wA, aA1);
    aB0 = fmaf(ls[0][k], wB, aB0);
    aB1 = fmaf(ls[1][k], wB, aB1);
  }
  pA[q][0][c] = aA0;
  pA[q][1][c] = aA1;
  pB[q][0][c] = aB0;
  pB[q][1][c] = aB1;
  __syncthreads();
  if (t < 128) {
    const int r = t >> 6, c2 = t & 63;
    const float s = pA[0][r][c2] + pA[1][r][c2] + pA[2][r][c2] + pA[3][r][c2];
    A[(j0 + r) * 64 + c2] = s;
    At[c2 * 512 + j0 + r] = s;
  } else {
    const int r = (t >> 6) & 1, c2 = t & 63;
    const float s = pB[0][r][c2] + pB[1][r][c2] + pB[2][r][c2] + pB[3][r][c2];
    B[(j0 + r) * 64 + c2] = s;
    Bt[c2 * 512 + j0 + r] = s;
  }
}

// ---------------------------------------------------------------------------
// K3: per-(s,c) BN affine via circular correlation. [body proven; inner loop
// unrolled 4]
__global__ __launch_bounds__(256) void k_cross(
    const float* __restrict__ At, const float* __restrict__ Bt,
    const float* __restrict__ dg, const float* __restrict__ dbt,
    float* __restrict__ alpha, float* __restrict__ beta) {
  __shared__ float a[512], bb[512];
  __shared__ float red[256];
  __shared__ float pc[4][64];
  const int t = threadIdx.x;
  const int c = blockIdx.x >> 3;
  const int s0 = (blockIdx.x & 7) * 64;
  const float a0 = At[c * 512 + t], a1 = At[c * 512 + 256 + t];
  const float b0 = Bt[c * 512 + t], b1 = Bt[c * 512 + 256 + t];
  a[t] = a0;
  a[t + 256] = a1;
  bb[t] = b0;
  bb[t + 256] = b1;
  red[t] = a0 + a1 + b0 + b1;
  __syncthreads();
  for (int o = 128; o; o >>= 1) {
    if (t < o) red[t] += red[t + o];
    __syncthreads();
  }
  const float S = red[0];
  __syncthreads();
  red[t] = a0 * a0 + a1 * a1 + b0 * b0 + b1 * b1;
  __syncthreads();
  for (int o = 128; o; o >>= 1) {
    if (t < o) red[t] += red[t + o];
    __syncthreads();
  }
  const float Q = red[0];
  const int sl = t & 63, part = t >> 6;
  const int s = s0 + sl;
  float cr = 0.f;
#pragma unroll 4
  for (int j = part * 128; j < part * 128 + 128; ++j)
    cr = fmaf(a[j], bb[(j - s - 1) & 511], cr);
  pc[part][sl] = cr;
  __syncthreads();
  if (t < 64) {
    const int ss = s0 + t;
    const float cross = pc[0][t] + pc[1][t] + pc[2][t] + pc[3][t];
    const float mean = S * (1.f / 512.f);
    const float var = (Q + 2.f * cross) * (1.f / 512.f) - mean * mean;
    const float gc = dg[c], bc = dbt[c];
    const float al = rsqrtf(var + 1e-5f) * gc;
    alpha[ss * 64 + c] = al;
    beta[ss * 64 + c] = bc - mean * al;
  }
}

// ---------------------------------------------------------------------------
// K4: fused mi+dis (bodies verbatim; mi = even blocks < 512; dis inner loop
// unrolled 4).
__global__ __launch_bounds__(256) void k_midis(
    const float* __restrict__ latent, const float* __restrict__ rpc,
    const float* __restrict__ A, const float* __restrict__ B,
    const float* __restrict__ alpha, const float* __restrict__ beta,
    const float* __restrict__ dW2, const float* __restrict__ db2,
    float* __restrict__ mi, float* __restrict__ dis,
    float2* __restrict__ miMM, float2* __restrict__ dsMM) {
  __shared__ __align__(16) float sm[15276];  // 61,104 B
  const int t = threadIdx.x;
  const bool is_mi = (blockIdx.x < 512) && ((blockIdx.x & 1) == 0);
  if (is_mi) {
    float* lats = sm;
    float* rpcs = sm + 4160;
    float* mt = sm + 8256;
    float* fmn = sm + 9344;
    float* fmx = sm + 9600;
    const int vb = blockIdx.x >> 1;
    const int jt = vb & 31, pt = vb >> 5;
    const int j0 = jt * 16, p0 = pt * 64;
    const int pl = t & 31, jg = t >> 5;
    float regL[16], regR[16];
#pragma unroll
    for (int i = 0; i < 16; ++i) {
      const int idx = t + i * 256;
      regL[i] = latent[(p0 + (idx >> 6)) * 256 + (idx & 63)];
      regR[i] = rpc[(j0 + (idx >> 8)) * 1024 + (idx & 255)];
    }
    float a00 = 0.f, a01 = 0.f, a10 = 0.f, a11 = 0.f;
    for (int kc = 0; kc < 4; ++kc) {
      __syncthreads();
#pragma unroll
      for (int i = 0; i < 16; ++i) {
        const int idx = t + i * 256;
        lats[(idx >> 6) * 65 + (idx & 63)] = regL[i];
        rpcs[idx] = regR[i];
      }
      __syncthreads();
      if (kc < 3) {
#pragma unroll
        for (int i = 0; i < 16; ++i) {
          const int idx = t + i * 256;
          regL[i] = latent[(p0 + (idx >> 6)) * 256 + (kc + 1) * 64 + (idx & 63)];
          regR[i] = rpc[(j0 + (idx >> 8)) * 1024 + (kc + 1) * 256 + (idx & 255)];
        }
      }
      const float4* rp0 = (const float4*)&rpcs[(jg * 2) * 256];
      const float4* rp1 = (const float4*)&rpcs[(jg * 2 + 1) * 256];
#pragma unroll 8
      for (int k = 0; k < 64; ++k) {
        const float l0 = lats[pl * 65 + k], l1 = lats[(pl + 32) * 65 + k];
        const float4 r0 = rp0[k];
        const float4 r1 = rp1[k];
        float v;
        v = fmaf(l0, r0.x, -r0.y);
        a00 += fmaxf(fmaf(-v, v, r0.z), -13.9f);
        v = fmaf(l1, r0.x, -r0.y);
        a01 += fmaxf(fmaf(-v, v, r0.z), -13.9f);
        v = fmaf(l0, r1.x, -r1.y);
        a10 += fmaxf(fmaf(-v, v, r1.z), -13.9f);
        v = fmaf(l1, r1.x, -r1.y);
        a11 += fmaxf(fmaf(-v, v, r1.z), -13.9f);
      }
    }
    a00 *= (1.f / 256.f);
    a01 *= (1.f / 256.f);
    a10 *= (1.f / 256.f);
    a11 *= (1.f / 256.f);
    __syncthreads();
    mt[pl * 17 + jg * 2] = a00;
    mt[(pl + 32) * 17 + jg * 2] = a01;
    mt[pl * 17 + jg * 2 + 1] = a10;
    mt[(pl + 32) * 17 + jg * 2 + 1] = a11;
    fmn[t] = fminf(fminf(a00, a01), fminf(a10, a11));
    fmx[t] = fmaxf(fmaxf(a00, a01), fmaxf(a10, a11));
    __syncthreads();
    for (int o = 128; o; o >>= 1) {
      if (t < o) {
        fmn[t] = fminf(fmn[t], fmn[t + o]);
        fmx[t] = fmaxf(fmx[t], fmx[t + o]);
      }
      __syncthreads();
    }
    if (t == 0) miMM[vb] = make_float2(fmn[0], fmx[0]);
    for (int i = t; i < 1024; i += 256) {
      const int pr = i >> 4, jc = i & 15;
      mi[(p0 + pr) * 512 + (j0 + jc)] = mt[pr * 17 + jc];
    }
  } else {
    float* As = sm;
    float* Bs = sm + 528;
    float* als = sm + 4752;
    float* bes = sm + 9438;
    float* w2s = sm + 14124;
    float* dt = sm + 14188;
    float* fmn = sm + 14764;
    float* fmx = sm + 15020;
    const int vb = (blockIdx.x < 512) ? (int)(blockIdx.x >> 1)
                                      : (int)(blockIdx.x - 256);
    const int jt = vb & 63, pt = vb >> 6;
    const int j0 = jt * 8, p0 = pt * 64;
    for (int idx = t; idx < 8 * 64; idx += 256)
      As[(idx >> 6) * 66 + (idx & 63)] = A[(j0 + (idx >> 6)) * 64 + (idx & 63)];
    for (int idx = t; idx < 64 * 64; idx += 256)
      Bs[(idx >> 6) * 66 + (idx & 63)] = B[(p0 + (idx >> 6)) * 64 + (idx & 63)];
    for (int idx = t; idx < 71 * 64; idx += 256) {
      const int r = idx >> 6, c = idx & 63;
      const int s = (j0 - p0 - 64 + r) & 511;
      als[r * 66 + c] = alpha[s * 64 + c];
      bes[r * 66 + c] = beta[s * 64 + c];
    }
    if (t < 64) w2s[t] = dW2[t];
    const float db2v = db2[0];
    __syncthreads();
    const int pl = t & 31, jg = t >> 5;
    const int rb0 = jg - pl + 63;
    const int rb1 = jg - pl + 31;
    float acc0 = 0.f, acc1 = 0.f;
#pragma unroll 4
    for (int c = 0; c < 64; c += 2) {
      const float2 av = *(const float2*)&As[jg * 66 + c];
      const float2 bv0 = *(const float2*)&Bs[pl * 66 + c];
      const float2 bv1 = *(const float2*)&Bs[(pl + 32) * 66 + c];
      const float2 al0 = *(const float2*)&als[rb0 * 66 + c];
      const float2 al1 = *(const float2*)&als[rb1 * 66 + c];
      const float2 be0 = *(const float2*)&bes[rb0 * 66 + c];
      const float2 be1 = *(const float2*)&bes[rb1 * 66 + c];
      const float2 w = *(const float2*)&w2s[c];
      float v;
      v = fmaf(av.x + bv0.x, al0.x, be0.x);
      v = (v >= 0.f) ? v : 0.01f * v;
      acc0 = fmaf(v, w.x, acc0);
      v = fmaf(av.y + bv0.y, al0.y, be0.y);
      v = (v >= 0.f) ? v : 0.01f * v;
      acc0 = fmaf(v, w.y, acc0);
      v = fmaf(av.x + bv1.x, al1.x, be1.x);
      v = (v >= 0.f) ? v : 0.01f * v;
      acc1 = fmaf(v, w.x, acc1);
      v = fmaf(av.y + bv1.y, al1.y, be1.y);
      v = (v >= 0.f) ? v : 0.01f * v;
      acc1 = fmaf(v, w.y, acc1);
    }
    acc0 = fabsf(acc0 + db2v);
    acc1 = fabsf(acc1 + db2v);
    dt[pl * 9 + jg] = acc0;
    dt[(pl + 32) * 9 + jg] = acc1;
    fmn[t] = fminf(acc0, acc1);
    fmx[t] = fmaxf(acc0, acc1);
    __syncthreads();
    for (int o = 128; o; o >>= 1) {
      if (t < o) {
        fmn[t] = fminf(fmn[t], fmn[t + o]);
        fmx[t] = fmaxf(fmx[t], fmx[t + o]);
      }
      __syncthreads();
    }
    if (t == 0) dsMM[vb] = make_float2(fmn[0], fmx[0]);
    for (int idx = t; idx < 512; idx += 256) {
      const int pr = idx >> 3, jc = idx & 7;
      dis[(p0 + pr) * 512 + (j0 + jc)] = dt[pr * 9 + jc];
    }
  }
}

// ---------------------------------------------------------------------------
// K5: minmax + normalize + sums + ticketed final (one float4 of mi/dis per
// thread). [unchanged — proven]
__global__ __launch_bounds__(256) void k_sumfin(
    const float* __restrict__ mi, const float* __restrict__ dis,
    const float2* __restrict__ miMM, const float2* __restrict__ dsMM,
    float* __restrict__ fin, const float* __restrict__ ent_part,
    const float* __restrict__ kl_part, float* __restrict__ out) {
  __shared__ float red1[256], red2[256], red3[256], red4[256];
  __shared__ int lastflag;
  const int t = threadIdx.x;
  {
    const float2 v = miMM[t];
    const float2 w0 = dsMM[t], w1 = dsMM[t + 256];
    red1[t] = v.x;
    red2[t] = v.y;
    red3[t] = fminf(w0.x, w1.x);
    red4[t] = fmaxf(w0.y, w1.y);
  }
  __syncthreads();
  for (int o = 128; o; o >>= 1) {
    if (t < o) {
      red1[t] = fminf(red1[t], red1[t + o]);
      red2[t] = fmaxf(red2[t], red2[t + o]);
      red3[t] = fminf(red3[t], red3[t + o]);
      red4[t] = fmaxf(red4[t], red4[t + o]);
    }
    __syncthreads();
  }
  const float mi_mn = red1[0], mi_mx = red2[0];
  const float d_mn = red3[0], d_mx = red4[0];
  __syncthreads();
  const float inv_mi = 1.f / (mi_mx - mi_mn + 1e-12f);
  const float inv_d = 1.f / (d_mx - d_mn + 1e-12f);
  float s1 = 0.f, s2 = 0.f;
  {
    const int idx = blockIdx.x * 256 + t;
    const float4 m4 = ((const float4*)mi)[idx];
    const float4 d4 = ((const float4*)dis)[idx];
    float mn_, dn_;
    mn_ = (m4.x - mi_mn) * inv_mi;
    dn_ = (d4.x - d_mn) * inv_d;
    s1 += fminf(mn_ + dn_, 1.0f);
    s2 += dn_;
    mn_ = (m4.y - mi_mn) * inv_mi;
    dn_ = (d4.y - d_mn) * inv_d;
    s1 += fminf(mn_ + dn_, 1.0f);
    s2 += dn_;
    mn_ = (m4.z - mi_mn) * inv_mi;
    dn_ = (d4.z - d_mn) * inv_d;
    s1 += fminf(mn_ + dn_, 1.0f);
    s2 += dn_;
    mn_ = (m4.w - mi_mn) * inv_mi;
    dn_ = (d4.w - d_mn) * inv_d;
    s1 += fminf(mn_ + dn_, 1.0f);
    s2 += dn_;
  }
  red1[t] = s1;
  red2[t] = s2;
  __syncthreads();
  for (int o = 128; o; o >>= 1) {
    if (t < o) {
      red1[t] += red1[t + o];
      red2[t] += red2[t + o];
    }
    __syncthreads();
  }
  if (t == 0) {
    atomicAdd(&fin[0], red1[0]);
    atomicAdd(&fin[1], red2[0]);
    __threadfence();
    const unsigned old = atomicAdd((unsigned*)&fin[2], 1u);
    lastflag = (old == 255u) ? 1 : 0;
  }
  __syncthreads();
  if (!lastflag) return;
  red1[t] = ent_part[t];
  red2[t] = kl_part[t];
  __syncthreads();
  for (int o = 128; o; o >>= 1) {
    if (t < o) {
      red1[t] += red1[t + o];
      red2[t] += red2[t + o];
    }
    __syncthreads();
  }
  if (t == 0) {
    const float S1 = atomicAdd(&fin[0], 0.f);
    const float S2 = atomicAdd(&fin[1], 0.f);
    const double entropy = (double)red1[0] / 512.0;
    const double kl = (double)red2[0] / 512.0;
    double l0 = entropy * 1e-4 + kl * 1e-4;
    if (l0 > 2000.0) l0 = 2000.0;
    const double ce = log1p(exp(l0));
    const double dis_loss = -(double)S1 / 512.0;
    const double dis_norm = (double)S2 / 512.0;
    const double c_dis = (dis_norm + dis_loss) / 512.0;
    out[0] = (float)(ce + c_dis);
    out[1] = (float)c_dis;
    out[2] = (float)ce;
  }
}

// ---------------------------------------------------------------------------
extern "C" void kernel_launch(void* const* d_in, const int* in_sizes, int n_in,
                              void* d_out, int out_size, void* d_ws,
                              size_t ws_size, hipStream_t stream) {
  (void)in_sizes;
  (void)n_in;
  (void)out_size;
  (void)ws_size;
  const float* obs = (const float*)d_in[0];
  const float* hid = (const float*)d_in[1];
  const float* eps = (const float*)d_in[2];
  const float* eW1 = (const float*)d_in[3];
  const float* eg = (const float*)d_in[5];
  const float* ebt = (const float*)d_in[6];
  const float* eW2 = (const float*)d_in[7];
  const float* eb2 = (const float*)d_in[8];
  const float* iW1 = (const float*)d_in[9];
  const float* ig = (const float*)d_in[11];
  const float* ibt = (const float*)d_in[12];
  const float* iW2 = (const float*)d_in[13];
  const float* ib2 = (const float*)d_in[14];
  const float* dW1 = (const float*)d_in[15];
  const float* dg = (const float*)d_in[17];
  const float* dbt = (const float*)d_in[18];
  const float* dW2 = (const float*)d_in[19];
  const float* db2 = (const float*)d_in[20];
  float* ws = (float*)d_ws;
  float* out = (float*)d_out;

  k_pre<<<256, 256, 0, stream>>>(obs, hid, eW1, iW1, ws + W_ENC_PRE,
                                 ws + W_INF_PRE, ws + W_PACC);
  k_latAB<<<256, 256, 0, stream>>>(ws + W_ENC_PRE, ws + W_INF_PRE, ws + W_PACC,
                                   eg, ebt, ig, ibt, eW2, eb2, iW2, ib2, eps,
                                   dW1, ws + W_LATENT, ws + W_RPC, ws + W_ENT,
                                   ws + W_KL, ws + W_A, ws + W_B, ws + W_AT,
                                   ws + W_BT, ws + W_FIN);
  k_cross<<<512, 256, 0, stream>>>(ws + W_AT, ws + W_BT, dg, dbt, ws + W_ALPHA,
                                   ws + W_BETA);
  k_midis<<<768, 256, 0, stream>>>(ws + W_LATENT, ws + W_RPC, ws + W_A,
                                   ws + W_B, ws + W_ALPHA, ws + W_BETA, dW2,
                                   db2, ws + W_MI, ws + W_DIS,
                                   (float2*)(ws + W_MIMM),
                                   (float2*)(ws + W_DSMM));
  k_sumfin<<<256, 256, 0, stream>>>(ws + W_MI, ws + W_DIS,
                                    (const float2*)(ws + W_MIMM),
                                    (const float2*)(ws + W_DSMM), ws + W_FIN,
                                    ws + W_ENT, ws + W_KL, out);
}